// Round 6
// baseline (93.910 us; speedup 1.0000x reference)
//
#include <hip/hip_runtime.h>

#define NBATCH 256
#define NCH 30
#define UF 4

__device__ __forceinline__ float fast_sqrt(float x) {
    float r;
    asm("v_sqrt_f32 %0, %1" : "=v"(r) : "v"(x));
    return r;
}

// Flat coalesced float4 mapping; grid ≡ 0 (mod 15) so 4*nthreads ≡ 0 (mod 30):
// each thread's channel phase c0 is loop-invariant, and the conf-holder thread
// h = (30*cell0+4)/4 is the SAME for every u-batch. Conf comes from the wave's
// own targ registers via __shfl; only wave-boundary lanes (~7/64) fall back to
// an exec-masked global load. No separate conf loads, no finish kernel.
// w(c, obj) = obj*A + B:  c<4 -> (5,0);  c==4 -> (0.5,0.5);  c>=5 -> (1,0).
__global__ __launch_bounds__(256, 4) void yolo_loss_kernel(
    const float* __restrict__ pred,
    const float* __restrict__ targ,
    float* __restrict__ out,
    int n4)
{
    const int nthreads = gridDim.x * blockDim.x;   // 5880*256 = 1,505,280
    const int tid = blockIdx.x * blockDim.x + threadIdx.x;

    const int e0    = tid * 4;              // first flat element (even phase)
    const int c0    = e0 % NCH;             // channel phase (loop-invariant)
    const int cell0 = e0 / NCH;
    const int cellh = (e0 + 3) / NCH;       // cell of last element (cell0 or +1)
    const int Flo0  = cell0 * NCH + 4;      // flat index of lo-cell conf
    const int Fhi0  = cellh * NCH + 4;      // flat index of hi-cell conf
    const int hlo   = Flo0 >> 2;            // holder THREAD (u-invariant!)
    const int hhi   = Fhi0 >> 2;
    const int lane_lo = hlo & 63;
    const int lane_hi = hhi & 63;
    const bool inw_lo = (hlo >> 6) == (tid >> 6);   // holder in my wave?
    const bool inw_hi = (hhi >> 6) == (tid >> 6);
    const int k_sel = (4 - c0 + NCH) % NCH; // my slot holding channel-4 (if <4)

    float A[4], B[4];
    bool  SQ[4], LO[4];
    #pragma unroll
    for (int k = 0; k < 4; ++k) {
        int c = c0 + k; if (c >= NCH) c -= NCH;
        SQ[k] = (c == 2 || c == 3);
        LO[k] = (c0 + k) < NCH;
        if (c < 4)       { A[k] = 5.0f; B[k] = 0.0f; }
        else if (c == 4) { A[k] = 0.5f; B[k] = 0.5f; }
        else             { A[k] = 1.0f; B[k] = 0.0f; }
    }

    const float4* __restrict__ p4 = reinterpret_cast<const float4*>(pred);
    const float4* __restrict__ t4 = reinterpret_cast<const float4*>(targ);

    float acc = 0.0f;
    int i = tid;
    int foff = 0;                            // flat-element offset of batch 0

    const int nmain = n4 / (nthreads * UF);  // 1 for the shipped shape
    for (int su = 0; su < nmain; ++su) {
        float4 pv[UF], tv[UF];
        #pragma unroll
        for (int u = 0; u < UF; ++u) pv[u] = p4[i + u * nthreads];
        #pragma unroll
        for (int u = 0; u < UF; ++u) tv[u] = t4[i + u * nthreads];

        #pragma unroll
        for (int u = 0; u < UF; ++u) {
            float pe[4] = {pv[u].x, pv[u].y, pv[u].z, pv[u].w};
            float te[4] = {tv[u].x, tv[u].y, tv[u].z, tv[u].w};
            // extract my channel-4 value (if I hold one) -> wave broadcast
            float sel = te[0];
            sel = (k_sel == 1) ? te[1] : sel;
            sel = (k_sel == 2) ? te[2] : sel;
            sel = (k_sel == 3) ? te[3] : sel;
            float clo = __shfl(sel, lane_lo, 64);
            float chi = __shfl(sel, lane_hi, 64);
            const int off_u = foff + 4 * u * nthreads;
            if (!inw_lo) clo = targ[Flo0 + off_u];   // rare boundary lanes
            if (!inw_hi) chi = targ[Fhi0 + off_u];
            float obj_lo = (clo == 1.0f) ? 1.0f : 0.0f;
            float obj_hi = (chi == 1.0f) ? 1.0f : 0.0f;
            #pragma unroll
            for (int k = 0; k < 4; ++k) {
                float p = pe[k], t = te[k];
                float dp = p - t;
                float ds = fast_sqrt(p) - fast_sqrt(t);
                float d   = SQ[k] ? ds : dp;
                float obj = LO[k] ? obj_lo : obj_hi;
                float w   = fmaf(obj, A[k], B[k]);
                acc = fmaf(w * d, d, acc);
            }
        }
        i    += UF * nthreads;
        foff += 4 * UF * nthreads;
    }

    // generic tail (empty for the shipped shape); direct conf loads
    for (; i < n4; i += nthreads) {
        const int off = i * 4 - e0;
        float4 pv = p4[i];
        float4 tv = t4[i];
        float clo = targ[Flo0 + off];
        float chi = targ[Fhi0 + off];
        float obj_lo = (clo == 1.0f) ? 1.0f : 0.0f;
        float obj_hi = (chi == 1.0f) ? 1.0f : 0.0f;
        float pe[4] = {pv.x, pv.y, pv.z, pv.w};
        float te[4] = {tv.x, tv.y, tv.z, tv.w};
        #pragma unroll
        for (int k = 0; k < 4; ++k) {
            float p = pe[k], t = te[k];
            float dp = p - t;
            float ds = fast_sqrt(p) - fast_sqrt(t);
            float d   = SQ[k] ? ds : dp;
            float obj = LO[k] ? obj_lo : obj_hi;
            float w   = fmaf(obj, A[k], B[k]);
            acc = fmaf(w * d, d, acc);
        }
    }

    // wave64 shuffle reduction -> block -> one atomic per block
    #pragma unroll
    for (int off = 32; off > 0; off >>= 1)
        acc += __shfl_down(acc, off, 64);

    __shared__ float lds[4];
    int lane = threadIdx.x & 63;
    int wid  = threadIdx.x >> 6;
    if (lane == 0) lds[wid] = acc;
    __syncthreads();
    if (threadIdx.x == 0) {
        float s = lds[0] + lds[1] + lds[2] + lds[3];
        atomicAdd(out, s * (1.0f / (float)NBATCH));
    }
}

extern "C" void kernel_launch(void* const* d_in, const int* in_sizes, int n_in,
                              void* d_out, int out_size, void* d_ws, size_t ws_size,
                              hipStream_t stream)
{
    const float* pred = (const float*)d_in[0];
    const float* targ = (const float*)d_in[1];
    float* out = (float*)d_out;

    hipMemsetAsync(out, 0, sizeof(float), stream);

    int n  = in_sizes[0];   // 24,084,480
    int n4 = n / 4;         // 6,021,120

    // blocks ≡ 0 (mod 15); 5880 -> exactly one UF=4 batch per thread, no tail.
    int blocks = 5880;
    yolo_loss_kernel<<<blocks, 256, 0, stream>>>(pred, targ, out, n4);
}

// Round 7
// 57.528 us; speedup vs baseline: 1.6324x; 1.6324x over previous
//
#include <hip/hip_runtime.h>

#define NBATCH 256
#define NCH 30

__device__ __forceinline__ float fast_sqrt(float x) {
    float r;
    asm("v_sqrt_f32 %0, %1" : "=v"(r) : "v"(x));
    return r;
}

// One float4-batch worth of loss. (sqrt(p)-sqrt(t))^2 == p + t - 2*sqrt(p*t):
// one v_sqrt per element instead of two, no square in that path.
__device__ __forceinline__ float quad_term(
    float4 pv, float4 tv, float clo, float chi,
    const float A[4], const float B[4], const bool SQ[4], const bool LO[4])
{
    float obj_lo = (clo == 1.0f) ? 1.0f : 0.0f;
    float obj_hi = (chi == 1.0f) ? 1.0f : 0.0f;
    float pe[4] = {pv.x, pv.y, pv.z, pv.w};
    float te[4] = {tv.x, tv.y, tv.z, tv.w};
    float acc = 0.0f;
    #pragma unroll
    for (int k = 0; k < 4; ++k) {
        float p = pe[k], t = te[k];
        float dns = p - t;
        float vns = dns * dns;                              // (p-t)^2
        float vsq = (p + t) - 2.0f * fast_sqrt(p * t);      // (sqrt p - sqrt t)^2
        float val = SQ[k] ? vsq : vns;
        float obj = LO[k] ? obj_lo : obj_hi;
        float w   = fmaf(obj, A[k], B[k]);
        acc = fmaf(w, val, acc);
    }
    return acc;
}

// Flat coalesced float4 mapping; grid ≡ 0 (mod 15) so 4*nthreads ≡ 0 (mod 30):
// channel phase c0 and conf flat-offsets are loop-invariant per thread.
// 8 float4/thread, hand-pipelined depth-4: ~24 VMEM in flight per wave.
// w(c, obj) = obj*A + B:  c<4 -> (5,0);  c==4 -> (0.5,0.5);  c>=5 -> (1,0).
__global__ __launch_bounds__(256, 4) void yolo_loss_kernel(
    const float* __restrict__ pred,
    const float* __restrict__ targ,
    float* __restrict__ out,
    int n4)
{
    const int T   = gridDim.x * blockDim.x;     // 2940*256 = 752,640
    const int tid = blockIdx.x * blockDim.x + threadIdx.x;

    const int e0    = tid * 4;
    const int c0    = e0 % NCH;                 // loop-invariant channel phase
    const int cell0 = e0 / NCH;
    const int cellh = (e0 + 3) / NCH;
    const int Flo0  = cell0 * NCH + 4;          // conf flat index (lo cell)
    const int Fhi0  = cellh * NCH + 4;          // conf flat index (hi cell)

    float A[4], B[4];
    bool  SQ[4], LO[4];
    #pragma unroll
    for (int k = 0; k < 4; ++k) {
        int c = c0 + k; if (c >= NCH) c -= NCH;
        SQ[k] = (c == 2 || c == 3);
        LO[k] = (c0 + k) < NCH;
        if (c < 4)       { A[k] = 5.0f; B[k] = 0.0f; }
        else if (c == 4) { A[k] = 0.5f; B[k] = 0.5f; }
        else             { A[k] = 1.0f; B[k] = 0.0f; }
    }

    const float4* __restrict__ p4 = reinterpret_cast<const float4*>(pred);
    const float4* __restrict__ t4 = reinterpret_cast<const float4*>(targ);

    float acc = 0.0f;

    if (n4 == 8 * T) {
        // ---- static pipelined path (shipped shape) ----
        const int T4 = T * 4;                   // conf offset step (elements)
        #define LD(M) \
            float4 pv##M = p4[tid + (M) * T]; \
            float4 tv##M = t4[tid + (M) * T]; \
            float clo##M = targ[Flo0 + (M) * T4]; \
            float chi##M = targ[Fhi0 + (M) * T4];
        #define CN(M) acc += quad_term(pv##M, tv##M, clo##M, chi##M, A, B, SQ, LO);

        LD(0) LD(1) LD(2) LD(3)
        CN(0) LD(4)
        CN(1) LD(5)
        CN(2) LD(6)
        CN(3) LD(7)
        CN(4) CN(5) CN(6) CN(7)
        #undef LD
        #undef CN
    } else {
        // ---- generic fallback (any n4; grid is always mult of 15) ----
        const int T4 = T * 4;
        int m = 0;
        for (int i = tid; i < n4; i += T, ++m) {
            float4 pv = p4[i];
            float4 tv = t4[i];
            float clo = targ[Flo0 + m * T4];
            float chi = targ[Fhi0 + m * T4];
            acc += quad_term(pv, tv, clo, chi, A, B, SQ, LO);
        }
    }

    // wave64 shuffle reduction -> block -> one atomic per block
    #pragma unroll
    for (int off = 32; off > 0; off >>= 1)
        acc += __shfl_down(acc, off, 64);

    __shared__ float lds[4];
    int lane = threadIdx.x & 63;
    int wid  = threadIdx.x >> 6;
    if (lane == 0) lds[wid] = acc;
    __syncthreads();
    if (threadIdx.x == 0) {
        float s = lds[0] + lds[1] + lds[2] + lds[3];
        atomicAdd(out, s * (1.0f / (float)NBATCH));
    }
}

extern "C" void kernel_launch(void* const* d_in, const int* in_sizes, int n_in,
                              void* d_out, int out_size, void* d_ws, size_t ws_size,
                              hipStream_t stream)
{
    const float* pred = (const float*)d_in[0];
    const float* targ = (const float*)d_in[1];
    float* out = (float*)d_out;

    hipMemsetAsync(out, 0, sizeof(float), stream);

    int n  = in_sizes[0];   // 24,084,480
    int n4 = n / 4;         // 6,021,120

    // 2940 ≡ 0 (mod 15): channel phase loop-invariant; 8 float4/thread exactly.
    int blocks = 2940;
    yolo_loss_kernel<<<blocks, 256, 0, stream>>>(pred, targ, out, n4);
}